// Round 12
// baseline (419.078 us; speedup 1.0000x reference)
//
#include <hip/hip_runtime.h>

typedef __attribute__((ext_vector_type(8))) short bf16x8;
typedef __attribute__((ext_vector_type(4))) float f32x4;

static constexpr int M = 8192;       // query rows (b*h*w)
static constexpr int N = 16384;      // feature vectors
static constexpr int K = 512;
// fast path: 256x256, 8 waves, single-barrier phases (R10-proven)
static constexpr int BM = 256;
static constexpr int BN = 256;
static constexpr int RBLK = M / BM;             // 32
static constexpr int CBLK = N / BN;             // 64
// fallback path (R0-proven): 128x128 bf16, in-kernel cast
static constexpr int BMs = 128;
static constexpr int BKs = 64;
static constexpr int KCHUNKS_S = K / BKs;         // 8
static constexpr int NGROUPS_S = 8;
static constexpr int GROUP_N_S = N / NGROUPS_S;   // 2048
static constexpr int NTILES_S = GROUP_N_S / 128;  // 16
static constexpr float F_INF = 3.0e38f;

__device__ __forceinline__ unsigned short f2bf(float f) {
    unsigned int u = __float_as_uint(f);
    return (unsigned short)((u + 0x7fffu + ((u >> 16) & 1u)) >> 16);
}

__device__ __forceinline__ void gl_lds16(const void* g, void* l) {
    __builtin_amdgcn_global_load_lds(
        (const __attribute__((address_space(1))) unsigned int*)g,
        (__attribute__((address_space(3))) unsigned int*)l, 16, 0, 0);
}

// ---------------- K0: fused cast(Q,F->bf16) + squared norms ----------------
__global__ void k_prep(const float* __restrict__ Q, const float* __restrict__ F,
                       unsigned short* __restrict__ Qb, unsigned short* __restrict__ Fb,
                       float* __restrict__ qn, float* __restrict__ fn) {
    int wid = blockIdx.x * 4 + (threadIdx.x >> 6);
    int lane = threadIdx.x & 63;
    bool isQ = wid < M;
    const float* src = isQ ? (Q + (size_t)wid * K) : (F + (size_t)(wid - M) * K);
    unsigned short* dst = isQ ? (Qb + (size_t)wid * K) : (Fb + (size_t)(wid - M) * K);
    const float4* p = reinterpret_cast<const float4*>(src) + lane * 2;
    float4 a = p[0], b = p[1];
    float s = a.x*a.x + a.y*a.y + a.z*a.z + a.w*a.w
            + b.x*b.x + b.y*b.y + b.z*b.z + b.w*b.w;
    bf16x8 v;
    v[0]=(short)f2bf(a.x); v[1]=(short)f2bf(a.y); v[2]=(short)f2bf(a.z); v[3]=(short)f2bf(a.w);
    v[4]=(short)f2bf(b.x); v[5]=(short)f2bf(b.y); v[6]=(short)f2bf(b.z); v[7]=(short)f2bf(b.w);
    *reinterpret_cast<bf16x8*>(dst + lane * 8) = v;
    #pragma unroll
    for (int d = 1; d < 64; d <<= 1) s += __shfl_xor(s, d);
    if (lane == 0) { if (isQ) qn[wid] = s; else fn[wid - M] = s; }
}

// ---------------- K1 (fallback): squared norms only ----------------
__global__ void k_norms(const float* __restrict__ Q, const float* __restrict__ F,
                        float* __restrict__ qn, float* __restrict__ fn) {
    int wid = blockIdx.x * 4 + (threadIdx.x >> 6);
    int lane = threadIdx.x & 63;
    const float* src = (wid < M) ? (Q + (size_t)wid * K) : (F + (size_t)(wid - M) * K);
    const float4* p = reinterpret_cast<const float4*>(src) + lane * 2;
    float4 a = p[0], b = p[1];
    float s = a.x*a.x + a.y*a.y + a.z*a.z + a.w*a.w
            + b.x*b.x + b.y*b.y + b.z*b.z + b.w*b.w;
    #pragma unroll
    for (int d = 1; d < 64; d <<= 1) s += __shfl_xor(s, d);
    if (lane == 0) { if (wid < M) qn[wid] = s; else fn[wid - M] = s; }
}

// ---------------- K2-fast: 256x256 single-barrier-phase min-GEMM (R10, minus setprio/swz) --
__global__ __launch_bounds__(512, 1)
void k_mingemm9(const unsigned short* __restrict__ Qb, const unsigned short* __restrict__ Fb,
                const float* __restrict__ qn, const float* __restrict__ fn,
                float* __restrict__ pv, unsigned int* __restrict__ pi) {
    __shared__ unsigned short As[2][2][8192];   // [parity][half][128x64] 64 KiB
    __shared__ unsigned short Bs[2][2][8192];   // 64 KiB
    __shared__ float redv[256][4];              // 4 KiB
    __shared__ unsigned int redi[256][4];       // 4 KiB

    const int tid = threadIdx.x;
    const int lane = tid & 63;
    const int wave = tid >> 6;        // 0..7
    const int wr = wave >> 2;         // 0..1
    const int wc = wave & 3;          // 0..3
    const int l15 = lane & 15, l4 = lane >> 4, l7 = lane & 7;
    const int r3 = lane >> 3;                 // row-within-8 for staging
    const int g8 = (lane & 7) ^ r3;           // pre-swizzled source 16B-slot

    // plain mapping (no XCD swizzle: data is L3-fit, swizzle costs ~2% per m160)
    const int wg = blockIdx.x;
    const int c_blk = wg & 63;                // 0..63
    const int r_blk = wg >> 6;                // 0..31
    const int row0 = r_blk * BM;
    const int col0 = c_blk * BN;

#define STAGE_A(t, hh) do {                                                        \
    _Pragma("unroll")                                                              \
    for (int i = 0; i < 2; ++i)                                                    \
        gl_lds16(Qb + (size_t)(row0 + (hh)*128 + i*64 + wave*8 + r3) * K           \
                    + (t)*64 + g8*8,                                               \
                 &As[(t)&1][hh][(i*64 + wave*8) * 64]);                            \
} while (0)
#define STAGE_B(t, hh) do {                                                        \
    _Pragma("unroll")                                                              \
    for (int i = 0; i < 2; ++i)                                                    \
        gl_lds16(Fb + (size_t)(col0 + (hh)*128 + i*64 + wave*8 + r3) * K           \
                    + (t)*64 + g8*8,                                               \
                 &Bs[(t)&1][hh][(i*64 + wave*8) * 64]);                            \
} while (0)

    f32x4 acc[8][4];
    #pragma unroll
    for (int a = 0; a < 8; ++a)
        #pragma unroll
        for (int b = 0; b < 4; ++b) acc[a][b] = f32x4{0.f, 0.f, 0.f, 0.f};

    bf16x8 afr[4][2], bfr[4][2];

// one phase: C++ ds_reads (compiler-counted lgkm); STAGE; MFMA; vmcnt; barrier
#define PHASE(t, s, STMT, VMN) do {                                                \
    if ((s) == 0) {                                                                \
        _Pragma("unroll")                                                          \
        for (int f = 0; f < 4; ++f)                                                \
            _Pragma("unroll")                                                      \
            for (int ks = 0; ks < 2; ++ks)                                         \
                afr[f][ks] = *reinterpret_cast<const bf16x8*>(                     \
                    &As[(t)&1][wr][(f*16 + l15)*64 + (((ks*4 + l4) ^ l7))*8]);     \
        _Pragma("unroll")                                                          \
        for (int f = 0; f < 2; ++f)                                                \
            _Pragma("unroll")                                                      \
            for (int ks = 0; ks < 2; ++ks)                                         \
                bfr[f][ks] = *reinterpret_cast<const bf16x8*>(                     \
                    &Bs[(t)&1][0][(wc*32 + f*16 + l15)*64 + (((ks*4 + l4) ^ l7))*8]); \
    } else if ((s) == 1) {                                                         \
        _Pragma("unroll")                                                          \
        for (int f = 0; f < 2; ++f)                                                \
            _Pragma("unroll")                                                      \
            for (int ks = 0; ks < 2; ++ks)                                         \
                bfr[2 + f][ks] = *reinterpret_cast<const bf16x8*>(                 \
                    &Bs[(t)&1][1][(wc*32 + f*16 + l15)*64 + (((ks*4 + l4) ^ l7))*8]); \
    } else if ((s) == 2) {                                                         \
        _Pragma("unroll")                                                          \
        for (int f = 0; f < 4; ++f)                                                \
            _Pragma("unroll")                                                      \
            for (int ks = 0; ks < 2; ++ks)                                         \
                afr[f][ks] = *reinterpret_cast<const bf16x8*>(                     \
                    &As[(t)&1][wr][((f+4)*16 + l15)*64 + (((ks*4 + l4) ^ l7))*8]); \
    }                                                                              \
    STMT;                                                                          \
    {                                                                              \
        const int AB = ((s) >= 2) ? 4 : 0;                                         \
        const int FJ = ((s) & 1) ? 2 : 0;                                          \
        _Pragma("unroll")                                                          \
        for (int f = 0; f < 4; ++f)                                                \
            _Pragma("unroll")                                                      \
            for (int j2 = 0; j2 < 2; ++j2)                                         \
                _Pragma("unroll")                                                  \
                for (int ks = 0; ks < 2; ++ks)                                     \
                    acc[AB + f][FJ + j2] = __builtin_amdgcn_mfma_f32_16x16x32_bf16(\
                        afr[f][ks], bfr[FJ + j2][ks], acc[AB + f][FJ + j2], 0,0,0);\
    }                                                                              \
    asm volatile("s_waitcnt vmcnt(" #VMN ")" ::: "memory");                        \
    __builtin_amdgcn_s_barrier();                                                  \
    __builtin_amdgcn_sched_barrier(0);                                             \
} while (0)

    // prologue: 7 half-tiles (tile0 full + B0,B1,A0 of tile1), oldest-first
    STAGE_B(0, 0); STAGE_B(0, 1); STAGE_A(0, 0); STAGE_A(0, 1);
    STAGE_B(1, 0); STAGE_B(1, 1); STAGE_A(1, 0);
    asm volatile("s_waitcnt vmcnt(6)" ::: "memory");   // tile 0 landed; 3 half-tiles in flight
    __builtin_amdgcn_s_barrier();
    __builtin_amdgcn_sched_barrier(0);

#define ITER(T)                                        \
    PHASE(T,     0, STAGE_A((T)+1, 1), 6);             \
    PHASE(T,     1, STAGE_B((T)+2, 0), 6);             \
    PHASE(T,     2, STAGE_B((T)+2, 1), 6);             \
    PHASE(T,     3, STAGE_A((T)+2, 0), 6);             \
    PHASE((T)+1, 0, STAGE_A((T)+2, 1), 6);             \
    PHASE((T)+1, 1, STAGE_B((T)+3, 0), 6);             \
    PHASE((T)+1, 2, STAGE_B((T)+3, 1), 6);             \
    PHASE((T)+1, 3, STAGE_A((T)+3, 0), 6);

    ITER(0)
    ITER(2)
    ITER(4)
    // tail (tiles 6,7): only A1(7) left to stage
    PHASE(6, 0, STAGE_A(7, 1), 6);
    PHASE(6, 1, (void)0, 6);
    PHASE(6, 2, (void)0, 6);
    PHASE(6, 3, (void)0, 0);
    PHASE(7, 0, (void)0, 0);
    PHASE(7, 1, (void)0, 0);
    PHASE(7, 2, (void)0, 0);
    PHASE(7, 3, (void)0, 0);
#undef ITER
#undef PHASE
#undef STAGE_A
#undef STAGE_B

    // ---- epilogue: d2 = |q|^2+|f|^2-2*dot; min+argmin per row over block's 256 cols ----
    float fnv[4];
    int colg[4];
    #pragma unroll
    for (int fj = 0; fj < 4; ++fj) {
        colg[fj] = col0 + (fj < 2 ? wc*32 + fj*16 : 128 + wc*32 + (fj - 2)*16) + l15;
        fnv[fj] = fn[colg[fj]];
    }
    #pragma unroll
    for (int fi = 0; fi < 8; ++fi) {
        #pragma unroll
        for (int j = 0; j < 4; ++j) {
            int rloc = wr*128 + fi*16 + l4*4 + j;
            float qv = qn[row0 + rloc];
            float v = F_INF; unsigned int ix = 0;
            #pragma unroll
            for (int fj = 0; fj < 4; ++fj) {
                float d2 = qv + fnv[fj] - 2.0f * acc[fi][fj][j];
                if (d2 < v) { v = d2; ix = (unsigned int)colg[fj]; }
            }
            #pragma unroll
            for (int d = 1; d < 16; d <<= 1) {
                float ov = __shfl_xor(v, d);
                unsigned int oi = (unsigned int)__shfl_xor((int)ix, d);
                if (ov < v) { v = ov; ix = oi; }
            }
            if (l15 == 0) { redv[rloc][wc] = v; redi[rloc][wc] = ix; }
        }
    }
    __syncthreads();
    if (tid < BM) {
        float v = redv[tid][0]; unsigned int ix = redi[tid][0];
        #pragma unroll
        for (int w2 = 1; w2 < 4; ++w2) {
            float ov = redv[tid][w2];
            if (ov < v) { v = ov; ix = redi[tid][w2]; }
        }
        pv[(size_t)(row0 + tid) * CBLK + c_blk] = v;
        pi[(size_t)(row0 + tid) * CBLK + c_blk] = ix;
    }
}

// ---------------- K2-slow (fallback): in-kernel cast version (R0-proven) ----------------
__global__ __launch_bounds__(256, 2)
void k_mingemm_cast(const float* __restrict__ Q, const float* __restrict__ F,
                    const float* __restrict__ qn, const float* __restrict__ fn,
                    float* __restrict__ pv, unsigned int* __restrict__ pi) {
    __shared__ unsigned short As[BMs * BKs];
    __shared__ unsigned short Bs[BMs * BKs];
    __shared__ float qn_t[BMs];
    __shared__ float fn_t[BMs];

    const int tid = threadIdx.x;
    const int lane = tid & 63;
    const int wave = tid >> 6;
    const int wr = wave >> 1, wc = wave & 1;
    const int l15 = lane & 15, l4 = lane >> 4;

    const int row0 = blockIdx.x * BMs;
    const int gbase = blockIdx.y * GROUP_N_S;

    const int srow = tid >> 3;
    const int p8 = tid & 7;
    const int g8 = p8 ^ (srow & 7);
    const float* pA[4];
    const float* pB[4];
    int dstOff[4];
    #pragma unroll
    for (int i = 0; i < 4; ++i) {
        int r = i * 32 + srow;
        pA[i] = Q + (size_t)(row0 + r) * K + g8 * 8;
        pB[i] = F + (size_t)(gbase + r) * K + g8 * 8;
        dstOff[i] = r * BKs + p8 * 8;
    }

    float mval[4][4];
    unsigned int midx[4][4];
    float qnv[4][4];
    #pragma unroll
    for (int a = 0; a < 4; ++a)
        #pragma unroll
        for (int b = 0; b < 4; ++b) { mval[a][b] = F_INF; midx[a][b] = 0; qnv[a][b] = 0.f; }

    for (int nt = 0; nt < NTILES_S; ++nt) {
        f32x4 acc[4][4];
        #pragma unroll
        for (int a = 0; a < 4; ++a)
            #pragma unroll
            for (int b = 0; b < 4; ++b) acc[a][b] = f32x4{0.f, 0.f, 0.f, 0.f};

        for (int kc = 0; kc < KCHUNKS_S; ++kc) {
            __syncthreads();
            #pragma unroll
            for (int i = 0; i < 4; ++i) {
                const float4* sa = reinterpret_cast<const float4*>(pA[i] + kc * BKs);
                float4 xa = sa[0], ya = sa[1];
                const float4* sb = reinterpret_cast<const float4*>(pB[i] + nt * (128 * K) + kc * BKs);
                float4 xb = sb[0], yb = sb[1];
                bf16x8 va, vb;
                va[0]=(short)f2bf(xa.x); va[1]=(short)f2bf(xa.y); va[2]=(short)f2bf(xa.z); va[3]=(short)f2bf(xa.w);
                va[4]=(short)f2bf(ya.x); va[5]=(short)f2bf(ya.y); va[6]=(short)f2bf(ya.z); va[7]=(short)f2bf(ya.w);
                vb[0]=(short)f2bf(xb.x); vb[1]=(short)f2bf(xb.y); vb[2]=(short)f2bf(xb.z); vb[3]=(short)f2bf(xb.w);
                vb[4]=(short)f2bf(yb.x); vb[5]=(short)f2bf(yb.y); vb[6]=(short)f2bf(yb.z); vb[7]=(short)f2bf(yb.w);
                *reinterpret_cast<bf16x8*>(&As[dstOff[i]]) = va;
                *reinterpret_cast<bf16x8*>(&Bs[dstOff[i]]) = vb;
            }
            if (kc == 0) {
                if (nt == 0 && tid < BMs) qn_t[tid] = qn[row0 + tid];
                if (tid < 128) fn_t[tid] = fn[gbase + nt * 128 + tid];
            }
            __syncthreads();
            if (nt == 0 && kc == 0) {
                #pragma unroll
                for (int fi = 0; fi < 4; ++fi)
                    #pragma unroll
                    for (int j = 0; j < 4; ++j)
                        qnv[fi][j] = qn_t[wr*64 + fi*16 + l4*4 + j];
            }
            #pragma unroll
            for (int ks = 0; ks < 2; ++ks) {
                const int gidx = ks * 4 + l4;
                bf16x8 af[4], bfv[4];
                #pragma unroll
                for (int fi = 0; fi < 4; ++fi) {
                    int r = wr*64 + fi*16 + l15;
                    int pg = gidx ^ (r & 7);
                    af[fi] = *reinterpret_cast<const bf16x8*>(&As[r*BKs + pg*8]);
                }
                #pragma unroll
                for (int fj = 0; fj < 4; ++fj) {
                    int r = wc*64 + fj*16 + l15;
                    int pg = gidx ^ (r & 7);
                    bfv[fj] = *reinterpret_cast<const bf16x8*>(&Bs[r*BKs + pg*8]);
                }
                #pragma unroll
                for (int fi = 0; fi < 4; ++fi)
                    #pragma unroll
                    for (int fj = 0; fj < 4; ++fj)
                        acc[fi][fj] = __builtin_amdgcn_mfma_f32_16x16x32_bf16(
                            af[fi], bfv[fj], acc[fi][fj], 0, 0, 0);
            }
        }
        const int colb = gbase + nt * 128 + wc * 64;
        float fnv[4];
        #pragma unroll
        for (int fj = 0; fj < 4; ++fj) fnv[fj] = fn_t[wc*64 + fj*16 + l15];
        #pragma unroll
        for (int fi = 0; fi < 4; ++fi) {
            #pragma unroll
            for (int j = 0; j < 4; ++j) {
                float qv = qnv[fi][j];
                #pragma unroll
                for (int fj = 0; fj < 4; ++fj) {
                    float d2 = qv + fnv[fj] - 2.0f * acc[fi][fj][j];
                    if (d2 < mval[fi][j]) {
                        mval[fi][j] = d2;
                        midx[fi][j] = (unsigned int)(colb + fj*16 + l15);
                    }
                }
            }
        }
    }
    #pragma unroll
    for (int fi = 0; fi < 4; ++fi) {
        #pragma unroll
        for (int j = 0; j < 4; ++j) {
            float v = mval[fi][j];
            unsigned int ix = midx[fi][j];
            #pragma unroll
            for (int d = 1; d < 16; d <<= 1) {
                float ov = __shfl_xor(v, d);
                unsigned int oi = (unsigned int)__shfl_xor((int)ix, d);
                if (ov < v) { v = ov; ix = oi; }
            }
            if (l15 == 0) {
                int rg = row0 + wr*64 + fi*16 + l4*4 + j;
                int pidx = rg * 16 + blockIdx.y * 2 + wc;
                pv[pidx] = v;
                pi[pidx] = ix;
            }
        }
    }
}

// ---------------- K3: merge partials, fp32-refine, fused per-batch argmax (atomic) -------
// asel[b] packs (sqrt-dist bits << 32) | (1023 - patch): atomicMax == argmax with
// first-index tiebreak (dist >= 0 so float bits are monotone).
__global__ void k_refine(const float* __restrict__ Q, const float* __restrict__ F,
                         const float* __restrict__ pv, const unsigned int* __restrict__ pi,
                         float* __restrict__ minD, unsigned long long* __restrict__ asel,
                         int PS) {
    int row = blockIdx.x * 4 + (threadIdx.x >> 6);
    int lane = threadIdx.x & 63;
    float v = F_INF; unsigned int ix = 0;
    for (int t = lane; t < PS; t += 64) {
        float nv = pv[(size_t)row*PS + t];
        if (nv < v) { v = nv; ix = pi[(size_t)row*PS + t]; }
    }
    #pragma unroll
    for (int d = 1; d < 64; d <<= 1) {
        float ov = __shfl_xor(v, d);
        unsigned int oi = (unsigned int)__shfl_xor((int)ix, d);
        if (ov < v) { v = ov; ix = oi; }
    }
    const float4* q = reinterpret_cast<const float4*>(Q + (size_t)row * K) + lane*2;
    const float4* f = reinterpret_cast<const float4*>(F + (size_t)ix * K) + lane*2;
    float4 a0 = q[0], a1 = q[1], b0 = f[0], b1 = f[1];
    float s = 0.f, dx;
    dx = a0.x-b0.x; s += dx*dx;  dx = a0.y-b0.y; s += dx*dx;
    dx = a0.z-b0.z; s += dx*dx;  dx = a0.w-b0.w; s += dx*dx;
    dx = a1.x-b1.x; s += dx*dx;  dx = a1.y-b1.y; s += dx*dx;
    dx = a1.z-b1.z; s += dx*dx;  dx = a1.w-b1.w; s += dx*dx;
    #pragma unroll
    for (int d = 1; d < 64; d <<= 1) s += __shfl_xor(s, d);
    if (lane == 0) {
        float dres = sqrtf(s);
        minD[row] = dres;
        unsigned long long pk =
            ((unsigned long long)__float_as_uint(dres) << 32) |
            (unsigned long long)(1023u - (unsigned int)(row & 1023));
        atomicMax(asel + (row >> 10), pk);
    }
}

// decode helper packed-argmax -> global row index
__device__ __forceinline__ unsigned int sel_decode(unsigned long long pk, int b) {
    return (unsigned int)(b * 1024 + (int)(1023u - (unsigned int)(pk & 0xffffffffu)));
}

// ---------------- K4 (fallback): per-batch argmax patch (first-index tiebreak) -----------
__global__ void k_argmax(const float* __restrict__ minD, unsigned int* __restrict__ sel) {
    __shared__ float sv[256];
    __shared__ int si[256];
    int b = blockIdx.x, tid = threadIdx.x;
    float bv = -F_INF; int bi = 0;
    for (int p = tid; p < 1024; p += 256) {
        float v = minD[b*1024 + p];
        if (v > bv) { bv = v; bi = p; }
    }
    sv[tid] = bv; si[tid] = bi;
    __syncthreads();
    for (int s = 128; s > 0; s >>= 1) {
        if (tid < s) {
            if (sv[tid+s] > sv[tid] || (sv[tid+s] == sv[tid] && si[tid+s] < si[tid])) {
                sv[tid] = sv[tid+s]; si[tid] = si[tid+s];
            }
        }
        __syncthreads();
    }
    if (tid == 0) sel[b] = (unsigned int)(b*1024 + si[0]);
}

// ---------------- K5-fast: distances from 8 selected rows to all F ----------------
__global__ void k_dist8(const float* __restrict__ Q, const float* __restrict__ F,
                        const unsigned long long* __restrict__ asel,
                        float* __restrict__ d2all) {
    __shared__ float qs[8][512];
    int tid = threadIdx.x;
    int lane = tid & 63, wave = tid >> 6;
    for (int i = tid; i < 8*512; i += 256) {
        int b = i >> 9;
        unsigned int srow = sel_decode(asel[b], b);
        qs[b][i & 511] = Q[(size_t)srow * K + (i & 511)];
    }
    __syncthreads();
    int base = blockIdx.x * 128 + wave * 32;
    for (int r = 0; r < 32; ++r) {
        int row = base + r;
        const float4* fp = reinterpret_cast<const float4*>(F + (size_t)row * K) + lane*2;
        float4 f0 = fp[0], f1 = fp[1];
        float fv[8] = {f0.x,f0.y,f0.z,f0.w,f1.x,f1.y,f1.z,f1.w};
        float accb[8];
        #pragma unroll
        for (int b = 0; b < 8; ++b) {
            float s = 0.f;
            #pragma unroll
            for (int e = 0; e < 8; ++e) {
                float d = fv[e] - qs[b][lane*8 + e];
                s += d * d;
            }
            accb[b] = s;
        }
        #pragma unroll
        for (int d = 1; d < 64; d <<= 1)
            #pragma unroll
            for (int b = 0; b < 8; ++b) accb[b] += __shfl_xor(accb[b], d);
        if (lane == 0) {
            #pragma unroll
            for (int b = 0; b < 8; ++b) d2all[b * N + row] = accb[b];
        }
    }
}

// ---------------- K6-fast: per-batch 9-smallest + score ----------------
__global__ void k_sel9(const float* __restrict__ d2all, float* __restrict__ out) {
    __shared__ float sv[256 * 10];
    int b = blockIdx.x, tid = threadIdx.x;
    float v[9];
    #pragma unroll
    for (int i = 0; i < 9; ++i) v[i] = F_INF;
    for (int i = tid; i < N; i += 256) {
        float x = d2all[b * N + i];
        #pragma unroll
        for (int s = 0; s < 9; ++s) {
            float lo = fminf(v[s], x), hi = fmaxf(v[s], x);
            v[s] = lo; x = hi;
        }
    }
    #pragma unroll
    for (int i = 0; i < 9; ++i) sv[tid*10 + i] = v[i];
    sv[tid*10 + 9] = F_INF;
    __syncthreads();
    for (int s = 128; s > 0; s >>= 1) {
        if (tid < s) {
            int ia = 1, ib = 1;
            float av = sv[tid*10], bv = sv[(tid+s)*10];
            float c[9];
            #pragma unroll
            for (int k = 0; k < 9; ++k) {
                bool ta = av <= bv;
                c[k] = ta ? av : bv;
                float na = sv[tid*10 + ia], nb = sv[(tid+s)*10 + ib];
                if (ta) { av = na; ++ia; } else { bv = nb; ++ib; }
            }
            #pragma unroll
            for (int k = 0; k < 9; ++k) sv[tid*10 + k] = c[k];
        }
        __syncthreads();
    }
    if (tid == 0) {
        float c[9];
        #pragma unroll
        for (int i = 0; i < 9; ++i) c[i] = sqrtf(fmaxf(sv[i], 0.f));
        float S = 0.f;
        #pragma unroll
        for (int i = 0; i < 9; ++i) S += expf(c[i] - c[8]);
        out[b] = c[0] * (1.f - 1.f / S);
    }
}

// ---------------- K5/K6-slow (fallback, R1-proven) ----------------
__global__ void k_top9(const float* __restrict__ Q, const float* __restrict__ F,
                       const unsigned int* __restrict__ sel, float* __restrict__ part9) {
    __shared__ float qs[512];
    __shared__ float dist[2048];
    __shared__ float rv[256];
    __shared__ int ri[256];
    int b = blockIdx.x >> 3, g = blockIdx.x & 7;
    int tid = threadIdx.x;
    unsigned int srow = sel[b];
    if (tid < 128)
        reinterpret_cast<float4*>(qs)[tid] =
            reinterpret_cast<const float4*>(Q + (size_t)srow * K)[tid];
    __syncthreads();
    #pragma unroll
    for (int e = 0; e < 8; ++e) {
        int fl = tid + 256*e;
        const float* fp = F + (size_t)(g*2048 + fl) * K;
        float s = 0.f;
        for (int k = 0; k < 512; k += 4) {
            float4 fv4 = *reinterpret_cast<const float4*>(fp + k);
            float d0 = qs[k]   - fv4.x;
            float d1 = qs[k+1] - fv4.y;
            float d2 = qs[k+2] - fv4.z;
            float d3 = qs[k+3] - fv4.w;
            s += d0*d0 + d1*d1 + d2*d2 + d3*d3;
        }
        dist[fl] = s;
    }
    __syncthreads();
    for (int it = 0; it < 9; ++it) {
        float lv = F_INF; int li = 0;
        #pragma unroll
        for (int e = 0; e < 8; ++e) {
            int idx = tid + 256*e;
            float v = dist[idx];
            if (v < lv) { lv = v; li = idx; }
        }
        rv[tid] = lv; ri[tid] = li;
        __syncthreads();
        for (int s = 128; s > 0; s >>= 1) {
            if (tid < s && rv[tid+s] < rv[tid]) { rv[tid] = rv[tid+s]; ri[tid] = ri[tid+s]; }
            __syncthreads();
        }
        if (tid == 0) {
            part9[(b*8+g)*9 + it] = rv[0];
            dist[ri[0]] = F_INF;
        }
        __syncthreads();
    }
}

__global__ void k_final(const float* __restrict__ part9, float* __restrict__ out) {
    int b = threadIdx.x;
    if (b >= 8) return;
    float arr[9];
    #pragma unroll
    for (int i = 0; i < 9; ++i) arr[i] = F_INF;
    for (int g = 0; g < 8; ++g)
        for (int i = 0; i < 9; ++i) {
            float v = part9[(b*8+g)*9 + i];
            #pragma unroll
            for (int s = 0; s < 9; ++s) {
                float lo = fminf(arr[s], v), hi = fmaxf(arr[s], v);
                arr[s] = lo; v = hi;
            }
        }
    float c[9];
    #pragma unroll
    for (int i = 0; i < 9; ++i) c[i] = sqrtf(fmaxf(arr[i], 0.f));
    float c8 = c[8], S = 0.f;
    #pragma unroll
    for (int i = 0; i < 9; ++i) S += expf(c[i] - c8);
    float w = 1.f - 1.f / S;
    out[b] = c[0] * w;
}

// ---------------- K7: combined (blur ∘ bilinear-resize) 256x32 matrix W + asel init ------
__global__ void k_wmat(float* __restrict__ W, unsigned long long* __restrict__ asel) {
    int idx = blockIdx.x * 256 + threadIdx.x;   // 8192
    if (idx < 8) asel[idx] = 0ull;              // zero-init packed argmax (ws is poisoned)
    int o = idx >> 5, j = idx & 31;
    float gsum = 0.f;
    #pragma unroll
    for (int u = 0; u < 33; ++u) { float d = (float)(u - 16); gsum += expf(-d*d * (1.f/32.f)); }
    float acc = 0.f;
    for (int u = 0; u < 33; ++u) {
        float d = (float)(u - 16);
        float gu = expf(-d*d * (1.f/32.f));
        int y = o + u - 16;
        y = y < 0 ? -y : (y > 255 ? 510 - y : y);   // reflect-101
        float xin = ((float)y + 0.5f) * 0.125f - 0.5f;
        float j0f = floorf(xin);
        int j0 = (int)j0f;
        float wfr = xin - j0f;
        float r;
        if (j0 < 0) r = (j == 0) ? 1.f : 0.f;
        else if (j0 >= 31) r = (j == 31) ? 1.f : 0.f;
        else r = (j == j0) ? (1.f - wfr) : ((j == j0 + 1) ? wfr : 0.f);
        acc += gu * r;
    }
    W[idx] = acc / gsum;
}

// ---------------- K8: mask = W * M32 * W^T per batch ----------------
__global__ void k_mask(const float* __restrict__ minD, const float* __restrict__ W,
                       float* __restrict__ outm) {
    __shared__ float Ms[1024];
    __shared__ float Ws[8192];
    __shared__ float Ts[8192];
    int b = blockIdx.x, tid = threadIdx.x;
    for (int i = tid; i < 1024; i += 256) Ms[i] = minD[b*1024 + i];
    for (int i = tid; i < 8192; i += 256) Ws[i] = W[i];
    __syncthreads();
    {
        int o = tid;
        float wrow[32];
        #pragma unroll
        for (int i = 0; i < 32; ++i) wrow[i] = Ws[o*32 + i];
        for (int j = 0; j < 32; ++j) {
            float s = 0.f;
            #pragma unroll
            for (int i = 0; i < 32; ++i) s += wrow[i] * Ms[i*32 + j];
            Ts[o*32 + j] = s;
        }
    }
    __syncthreads();
    {
        int p = tid;
        float wp[32];
        #pragma unroll
        for (int j = 0; j < 32; ++j) wp[j] = Ws[p*32 + j];
        float* dst = outm + (size_t)b * 65536;
        for (int o = 0; o < 256; ++o) {
            float s = 0.f;
            #pragma unroll
            for (int j = 0; j < 32; ++j) s += Ts[o*32 + j] * wp[j];
            dst[o*256 + p] = s;
        }
    }
}

extern "C" void kernel_launch(void* const* d_in, const int* in_sizes, int n_in,
                              void* d_out, int out_size, void* d_ws, size_t ws_size,
                              hipStream_t stream) {
    const float* Q = (const float*)d_in[0];          // [8192, 512]
    const float* F = (const float*)d_in[1];          // [16384, 512]
    float* out = (float*)d_out;                      // [8] score_out + [8*256*256] mask

    const size_t smallFloats = (size_t)8192*64*2 + 8192 + 32 + 576 + (size_t)8*N + 8192 + 16384 + 8192;
    const size_t REQ = smallFloats*4 + (size_t)M*K*2 + (size_t)N*K*2;
    const bool fast = ws_size >= REQ;

    float* ws = (float*)d_ws;
    float* pv = ws;                                    // stride 64 (fast) / 16 (slow)
    unsigned int* pi = (unsigned int*)(pv + 8192*64);
    float* minD = (float*)(pi + 8192*64);              // 8192
    unsigned long long* asel = (unsigned long long*)(minD + 8192);   // 8 u64 (16 floats)
    unsigned int* sel = (unsigned int*)(asel + 8);     // 8 u32 (fallback path)
    float* part9 = (float*)(sel + 8);                  // 576
    float* d2all = part9 + 576;                        // 8*16384 (fast only)
    float* qn = d2all + (size_t)8*N;                   // 8192
    float* fn = qn + 8192;                             // 16384
    float* W  = fn + 16384;                            // 8192
    unsigned short* Qb = (unsigned short*)(W + 8192);  // 8MB bf16 (fast only)
    unsigned short* Fb = Qb + (size_t)M*K;             // 16MB bf16 (fast only)

    k_wmat <<<dim3(32), 256, 0, stream>>>(W, asel);
    if (fast) {
        k_prep <<<dim3((M + N) / 4), 256, 0, stream>>>(Q, F, Qb, Fb, qn, fn);
        k_mingemm9<<<dim3(RBLK * CBLK), 512, 0, stream>>>(Qb, Fb, qn, fn, pv, pi);
        k_refine<<<dim3(M / 4), 256, 0, stream>>>(Q, F, pv, pi, minD, asel, 64);
        k_dist8<<<dim3(N / 128), 256, 0, stream>>>(Q, F, asel, d2all);
        k_sel9 <<<dim3(8), 256, 0, stream>>>(d2all, out);
    } else {
        k_norms<<<dim3((M + N) / 4), 256, 0, stream>>>(Q, F, qn, fn);
        k_mingemm_cast<<<dim3(M / BMs, NGROUPS_S), 256, 0, stream>>>(Q, F, qn, fn, pv, pi);
        k_refine<<<dim3(M / 4), 256, 0, stream>>>(Q, F, pv, pi, minD, asel, 16);
        k_argmax<<<dim3(8), 256, 0, stream>>>(minD, sel);
        k_top9 <<<dim3(64), 256, 0, stream>>>(Q, F, sel, part9);
        k_final<<<dim3(1), 64, 0, stream>>>(part9, out);
    }
    k_mask <<<dim3(8), 256, 0, stream>>>(minD, W, out + 8);
}

// Round 13
// 329.524 us; speedup vs baseline: 1.2718x; 1.2718x over previous
//
#include <hip/hip_runtime.h>

typedef __attribute__((ext_vector_type(8))) short bf16x8;
typedef __attribute__((ext_vector_type(4))) float f32x4;

static constexpr int M = 8192;       // query rows (b*h*w)
static constexpr int N = 16384;      // feature vectors
static constexpr int K = 512;
// fast path: 256x256, 8 waves, single-barrier phases (R12-proven GEMM)
static constexpr int BM = 256;
static constexpr int BN = 256;
static constexpr int RBLK = M / BM;             // 32
static constexpr int CBLK = N / BN;             // 64
// fallback path (R0-proven): 128x128 bf16, in-kernel cast
static constexpr int BMs = 128;
static constexpr int BKs = 64;
static constexpr int KCHUNKS_S = K / BKs;         // 8
static constexpr int NGROUPS_S = 8;
static constexpr int GROUP_N_S = N / NGROUPS_S;   // 2048
static constexpr int NTILES_S = GROUP_N_S / 128;  // 16
static constexpr float F_INF = 3.0e38f;

__device__ __forceinline__ unsigned short f2bf(float f) {
    unsigned int u = __float_as_uint(f);
    return (unsigned short)((u + 0x7fffu + ((u >> 16) & 1u)) >> 16);
}

__device__ __forceinline__ void gl_lds16(const void* g, void* l) {
    __builtin_amdgcn_global_load_lds(
        (const __attribute__((address_space(1))) unsigned int*)g,
        (__attribute__((address_space(3))) unsigned int*)l, 16, 0, 0);
}

// ---------------- K0: fused cast(Q,F->bf16) + squared norms ----------------
__global__ void k_prep(const float* __restrict__ Q, const float* __restrict__ F,
                       unsigned short* __restrict__ Qb, unsigned short* __restrict__ Fb,
                       float* __restrict__ qn, float* __restrict__ fn) {
    int wid = blockIdx.x * 4 + (threadIdx.x >> 6);
    int lane = threadIdx.x & 63;
    bool isQ = wid < M;
    const float* src = isQ ? (Q + (size_t)wid * K) : (F + (size_t)(wid - M) * K);
    unsigned short* dst = isQ ? (Qb + (size_t)wid * K) : (Fb + (size_t)(wid - M) * K);
    const float4* p = reinterpret_cast<const float4*>(src) + lane * 2;
    float4 a = p[0], b = p[1];
    float s = a.x*a.x + a.y*a.y + a.z*a.z + a.w*a.w
            + b.x*b.x + b.y*b.y + b.z*b.z + b.w*b.w;
    bf16x8 v;
    v[0]=(short)f2bf(a.x); v[1]=(short)f2bf(a.y); v[2]=(short)f2bf(a.z); v[3]=(short)f2bf(a.w);
    v[4]=(short)f2bf(b.x); v[5]=(short)f2bf(b.y); v[6]=(short)f2bf(b.z); v[7]=(short)f2bf(b.w);
    *reinterpret_cast<bf16x8*>(dst + lane * 8) = v;
    #pragma unroll
    for (int d = 1; d < 64; d <<= 1) s += __shfl_xor(s, d);
    if (lane == 0) { if (isQ) qn[wid] = s; else fn[wid - M] = s; }
}

// ---------------- K1 (fallback): squared norms only ----------------
__global__ void k_norms(const float* __restrict__ Q, const float* __restrict__ F,
                        float* __restrict__ qn, float* __restrict__ fn) {
    int wid = blockIdx.x * 4 + (threadIdx.x >> 6);
    int lane = threadIdx.x & 63;
    const float* src = (wid < M) ? (Q + (size_t)wid * K) : (F + (size_t)(wid - M) * K);
    const float4* p = reinterpret_cast<const float4*>(src) + lane * 2;
    float4 a = p[0], b = p[1];
    float s = a.x*a.x + a.y*a.y + a.z*a.z + a.w*a.w
            + b.x*b.x + b.y*b.y + b.z*b.z + b.w*b.w;
    #pragma unroll
    for (int d = 1; d < 64; d <<= 1) s += __shfl_xor(s, d);
    if (lane == 0) { if (wid < M) qn[wid] = s; else fn[wid - M] = s; }
}

// ---------------- K2-fast: 256x256 single-barrier-phase min-GEMM (R12-proven) ----------
__global__ __launch_bounds__(512, 1)
void k_mingemm9(const unsigned short* __restrict__ Qb, const unsigned short* __restrict__ Fb,
                const float* __restrict__ qn, const float* __restrict__ fn,
                float* __restrict__ pv, unsigned int* __restrict__ pi) {
    __shared__ unsigned short As[2][2][8192];   // [parity][half][128x64] 64 KiB
    __shared__ unsigned short Bs[2][2][8192];   // 64 KiB
    __shared__ float redv[256][4];              // 4 KiB
    __shared__ unsigned int redi[256][4];       // 4 KiB

    const int tid = threadIdx.x;
    const int lane = tid & 63;
    const int wave = tid >> 6;        // 0..7
    const int wr = wave >> 2;         // 0..1
    const int wc = wave & 3;          // 0..3
    const int l15 = lane & 15, l4 = lane >> 4, l7 = lane & 7;
    const int r3 = lane >> 3;                 // row-within-8 for staging
    const int g8 = (lane & 7) ^ r3;           // pre-swizzled source 16B-slot

    const int wg = blockIdx.x;
    const int c_blk = wg & 63;                // 0..63
    const int r_blk = wg >> 6;                // 0..31
    const int row0 = r_blk * BM;
    const int col0 = c_blk * BN;

#define STAGE_A(t, hh) do {                                                        \
    _Pragma("unroll")                                                              \
    for (int i = 0; i < 2; ++i)                                                    \
        gl_lds16(Qb + (size_t)(row0 + (hh)*128 + i*64 + wave*8 + r3) * K           \
                    + (t)*64 + g8*8,                                               \
                 &As[(t)&1][hh][(i*64 + wave*8) * 64]);                            \
} while (0)
#define STAGE_B(t, hh) do {                                                        \
    _Pragma("unroll")                                                              \
    for (int i = 0; i < 2; ++i)                                                    \
        gl_lds16(Fb + (size_t)(col0 + (hh)*128 + i*64 + wave*8 + r3) * K           \
                    + (t)*64 + g8*8,                                               \
                 &Bs[(t)&1][hh][(i*64 + wave*8) * 64]);                            \
} while (0)

    f32x4 acc[8][4];
    #pragma unroll
    for (int a = 0; a < 8; ++a)
        #pragma unroll
        for (int b = 0; b < 4; ++b) acc[a][b] = f32x4{0.f, 0.f, 0.f, 0.f};

    bf16x8 afr[4][2], bfr[4][2];

#define PHASE(t, s, STMT, VMN) do {                                                \
    if ((s) == 0) {                                                                \
        _Pragma("unroll")                                                          \
        for (int f = 0; f < 4; ++f)                                                \
            _Pragma("unroll")                                                      \
            for (int ks = 0; ks < 2; ++ks)                                         \
                afr[f][ks] = *reinterpret_cast<const bf16x8*>(                     \
                    &As[(t)&1][wr][(f*16 + l15)*64 + (((ks*4 + l4) ^ l7))*8]);     \
        _Pragma("unroll")                                                          \
        for (int f = 0; f < 2; ++f)                                                \
            _Pragma("unroll")                                                      \
            for (int ks = 0; ks < 2; ++ks)                                         \
                bfr[f][ks] = *reinterpret_cast<const bf16x8*>(                     \
                    &Bs[(t)&1][0][(wc*32 + f*16 + l15)*64 + (((ks*4 + l4) ^ l7))*8]); \
    } else if ((s) == 1) {                                                         \
        _Pragma("unroll")                                                          \
        for (int f = 0; f < 2; ++f)                                                \
            _Pragma("unroll")                                                      \
            for (int ks = 0; ks < 2; ++ks)                                         \
                bfr[2 + f][ks] = *reinterpret_cast<const bf16x8*>(                 \
                    &Bs[(t)&1][1][(wc*32 + f*16 + l15)*64 + (((ks*4 + l4) ^ l7))*8]); \
    } else if ((s) == 2) {                                                         \
        _Pragma("unroll")                                                          \
        for (int f = 0; f < 4; ++f)                                                \
            _Pragma("unroll")                                                      \
            for (int ks = 0; ks < 2; ++ks)                                         \
                afr[f][ks] = *reinterpret_cast<const bf16x8*>(                     \
                    &As[(t)&1][wr][((f+4)*16 + l15)*64 + (((ks*4 + l4) ^ l7))*8]); \
    }                                                                              \
    STMT;                                                                          \
    {                                                                              \
        const int AB = ((s) >= 2) ? 4 : 0;                                         \
        const int FJ = ((s) & 1) ? 2 : 0;                                          \
        _Pragma("unroll")                                                          \
        for (int f = 0; f < 4; ++f)                                                \
            _Pragma("unroll")                                                      \
            for (int j2 = 0; j2 < 2; ++j2)                                         \
                _Pragma("unroll")                                                  \
                for (int ks = 0; ks < 2; ++ks)                                     \
                    acc[AB + f][FJ + j2] = __builtin_amdgcn_mfma_f32_16x16x32_bf16(\
                        afr[f][ks], bfr[FJ + j2][ks], acc[AB + f][FJ + j2], 0,0,0);\
    }                                                                              \
    asm volatile("s_waitcnt vmcnt(" #VMN ")" ::: "memory");                        \
    __builtin_amdgcn_s_barrier();                                                  \
    __builtin_amdgcn_sched_barrier(0);                                             \
} while (0)

    // prologue: 7 half-tiles (tile0 full + B0,B1,A0 of tile1), oldest-first
    STAGE_B(0, 0); STAGE_B(0, 1); STAGE_A(0, 0); STAGE_A(0, 1);
    STAGE_B(1, 0); STAGE_B(1, 1); STAGE_A(1, 0);
    asm volatile("s_waitcnt vmcnt(6)" ::: "memory");   // tile 0 landed; 3 half-tiles in flight
    __builtin_amdgcn_s_barrier();
    __builtin_amdgcn_sched_barrier(0);

#define ITER(T)                                        \
    PHASE(T,     0, STAGE_A((T)+1, 1), 6);             \
    PHASE(T,     1, STAGE_B((T)+2, 0), 6);             \
    PHASE(T,     2, STAGE_B((T)+2, 1), 6);             \
    PHASE(T,     3, STAGE_A((T)+2, 0), 6);             \
    PHASE((T)+1, 0, STAGE_A((T)+2, 1), 6);             \
    PHASE((T)+1, 1, STAGE_B((T)+3, 0), 6);             \
    PHASE((T)+1, 2, STAGE_B((T)+3, 1), 6);             \
    PHASE((T)+1, 3, STAGE_A((T)+3, 0), 6);

    ITER(0)
    ITER(2)
    ITER(4)
    // tail (tiles 6,7): only A1(7) left to stage
    PHASE(6, 0, STAGE_A(7, 1), 6);
    PHASE(6, 1, (void)0, 6);
    PHASE(6, 2, (void)0, 6);
    PHASE(6, 3, (void)0, 0);
    PHASE(7, 0, (void)0, 0);
    PHASE(7, 1, (void)0, 0);
    PHASE(7, 2, (void)0, 0);
    PHASE(7, 3, (void)0, 0);
#undef ITER
#undef PHASE
#undef STAGE_A
#undef STAGE_B

    // ---- epilogue: d2 = |q|^2+|f|^2-2*dot; min+argmin per row over block's 256 cols ----
    float fnv[4];
    int colg[4];
    #pragma unroll
    for (int fj = 0; fj < 4; ++fj) {
        colg[fj] = col0 + (fj < 2 ? wc*32 + fj*16 : 128 + wc*32 + (fj - 2)*16) + l15;
        fnv[fj] = fn[colg[fj]];
    }
    #pragma unroll
    for (int fi = 0; fi < 8; ++fi) {
        #pragma unroll
        for (int j = 0; j < 4; ++j) {
            int rloc = wr*128 + fi*16 + l4*4 + j;
            float qv = qn[row0 + rloc];
            float v = F_INF; unsigned int ix = 0;
            #pragma unroll
            for (int fj = 0; fj < 4; ++fj) {
                float d2 = qv + fnv[fj] - 2.0f * acc[fi][fj][j];
                if (d2 < v) { v = d2; ix = (unsigned int)colg[fj]; }
            }
            #pragma unroll
            for (int d = 1; d < 16; d <<= 1) {
                float ov = __shfl_xor(v, d);
                unsigned int oi = (unsigned int)__shfl_xor((int)ix, d);
                if (ov < v) { v = ov; ix = oi; }
            }
            if (l15 == 0) { redv[rloc][wc] = v; redi[rloc][wc] = ix; }
        }
    }
    __syncthreads();
    if (tid < BM) {
        float v = redv[tid][0]; unsigned int ix = redi[tid][0];
        #pragma unroll
        for (int w2 = 1; w2 < 4; ++w2) {
            float ov = redv[tid][w2];
            if (ov < v) { v = ov; ix = redi[tid][w2]; }
        }
        pv[(size_t)(row0 + tid) * CBLK + c_blk] = v;
        pi[(size_t)(row0 + tid) * CBLK + c_blk] = ix;
    }
}

// ---------------- K2-slow (fallback): in-kernel cast version (R0-proven) ----------------
__global__ __launch_bounds__(256, 2)
void k_mingemm_cast(const float* __restrict__ Q, const float* __restrict__ F,
                    const float* __restrict__ qn, const float* __restrict__ fn,
                    float* __restrict__ pv, unsigned int* __restrict__ pi) {
    __shared__ unsigned short As[BMs * BKs];
    __shared__ unsigned short Bs[BMs * BKs];
    __shared__ float qn_t[BMs];
    __shared__ float fn_t[BMs];

    const int tid = threadIdx.x;
    const int lane = tid & 63;
    const int wave = tid >> 6;
    const int wr = wave >> 1, wc = wave & 1;
    const int l15 = lane & 15, l4 = lane >> 4;

    const int row0 = blockIdx.x * BMs;
    const int gbase = blockIdx.y * GROUP_N_S;

    const int srow = tid >> 3;
    const int p8 = tid & 7;
    const int g8 = p8 ^ (srow & 7);
    const float* pA[4];
    const float* pB[4];
    int dstOff[4];
    #pragma unroll
    for (int i = 0; i < 4; ++i) {
        int r = i * 32 + srow;
        pA[i] = Q + (size_t)(row0 + r) * K + g8 * 8;
        pB[i] = F + (size_t)(gbase + r) * K + g8 * 8;
        dstOff[i] = r * BKs + p8 * 8;
    }

    float mval[4][4];
    unsigned int midx[4][4];
    float qnv[4][4];
    #pragma unroll
    for (int a = 0; a < 4; ++a)
        #pragma unroll
        for (int b = 0; b < 4; ++b) { mval[a][b] = F_INF; midx[a][b] = 0; qnv[a][b] = 0.f; }

    for (int nt = 0; nt < NTILES_S; ++nt) {
        f32x4 acc[4][4];
        #pragma unroll
        for (int a = 0; a < 4; ++a)
            #pragma unroll
            for (int b = 0; b < 4; ++b) acc[a][b] = f32x4{0.f, 0.f, 0.f, 0.f};

        for (int kc = 0; kc < KCHUNKS_S; ++kc) {
            __syncthreads();
            #pragma unroll
            for (int i = 0; i < 4; ++i) {
                const float4* sa = reinterpret_cast<const float4*>(pA[i] + kc * BKs);
                float4 xa = sa[0], ya = sa[1];
                const float4* sb = reinterpret_cast<const float4*>(pB[i] + nt * (128 * K) + kc * BKs);
                float4 xb = sb[0], yb = sb[1];
                bf16x8 va, vb;
                va[0]=(short)f2bf(xa.x); va[1]=(short)f2bf(xa.y); va[2]=(short)f2bf(xa.z); va[3]=(short)f2bf(xa.w);
                va[4]=(short)f2bf(ya.x); va[5]=(short)f2bf(ya.y); va[6]=(short)f2bf(ya.z); va[7]=(short)f2bf(ya.w);
                vb[0]=(short)f2bf(xb.x); vb[1]=(short)f2bf(xb.y); vb[2]=(short)f2bf(xb.z); vb[3]=(short)f2bf(xb.w);
                vb[4]=(short)f2bf(yb.x); vb[5]=(short)f2bf(yb.y); vb[6]=(short)f2bf(yb.z); vb[7]=(short)f2bf(yb.w);
                *reinterpret_cast<bf16x8*>(&As[dstOff[i]]) = va;
                *reinterpret_cast<bf16x8*>(&Bs[dstOff[i]]) = vb;
            }
            if (kc == 0) {
                if (nt == 0 && tid < BMs) qn_t[tid] = qn[row0 + tid];
                if (tid < 128) fn_t[tid] = fn[gbase + nt * 128 + tid];
            }
            __syncthreads();
            if (nt == 0 && kc == 0) {
                #pragma unroll
                for (int fi = 0; fi < 4; ++fi)
                    #pragma unroll
                    for (int j = 0; j < 4; ++j)
                        qnv[fi][j] = qn_t[wr*64 + fi*16 + l4*4 + j];
            }
            #pragma unroll
            for (int ks = 0; ks < 2; ++ks) {
                const int gidx = ks * 4 + l4;
                bf16x8 af[4], bfv[4];
                #pragma unroll
                for (int fi = 0; fi < 4; ++fi) {
                    int r = wr*64 + fi*16 + l15;
                    int pg = gidx ^ (r & 7);
                    af[fi] = *reinterpret_cast<const bf16x8*>(&As[r*BKs + pg*8]);
                }
                #pragma unroll
                for (int fj = 0; fj < 4; ++fj) {
                    int r = wc*64 + fj*16 + l15;
                    int pg = gidx ^ (r & 7);
                    bfv[fj] = *reinterpret_cast<const bf16x8*>(&Bs[r*BKs + pg*8]);
                }
                #pragma unroll
                for (int fi = 0; fi < 4; ++fi)
                    #pragma unroll
                    for (int fj = 0; fj < 4; ++fj)
                        acc[fi][fj] = __builtin_amdgcn_mfma_f32_16x16x32_bf16(
                            af[fi], bfv[fj], acc[fi][fj], 0, 0, 0);
            }
        }
        const int colb = gbase + nt * 128 + wc * 64;
        float fnv[4];
        #pragma unroll
        for (int fj = 0; fj < 4; ++fj) fnv[fj] = fn_t[wc*64 + fj*16 + l15];
        #pragma unroll
        for (int fi = 0; fi < 4; ++fi) {
            #pragma unroll
            for (int j = 0; j < 4; ++j) {
                float qv = qnv[fi][j];
                #pragma unroll
                for (int fj = 0; fj < 4; ++fj) {
                    float d2 = qv + fnv[fj] - 2.0f * acc[fi][fj][j];
                    if (d2 < mval[fi][j]) {
                        mval[fi][j] = d2;
                        midx[fi][j] = (unsigned int)(colb + fj*16 + l15);
                    }
                }
            }
        }
    }
    #pragma unroll
    for (int fi = 0; fi < 4; ++fi) {
        #pragma unroll
        for (int j = 0; j < 4; ++j) {
            float v = mval[fi][j];
            unsigned int ix = midx[fi][j];
            #pragma unroll
            for (int d = 1; d < 16; d <<= 1) {
                float ov = __shfl_xor(v, d);
                unsigned int oi = (unsigned int)__shfl_xor((int)ix, d);
                if (ov < v) { v = ov; ix = oi; }
            }
            if (l15 == 0) {
                int rg = row0 + wr*64 + fi*16 + l4*4 + j;
                int pidx = rg * 16 + blockIdx.y * 2 + wc;
                pv[pidx] = v;
                pi[pidx] = ix;
            }
        }
    }
}

// ---------------- K3: merge partials, fp32-refine the min distance ----------------
__global__ void k_refine(const float* __restrict__ Q, const float* __restrict__ F,
                         const float* __restrict__ pv, const unsigned int* __restrict__ pi,
                         float* __restrict__ minD, int PS) {
    int row = blockIdx.x * 4 + (threadIdx.x >> 6);
    int lane = threadIdx.x & 63;
    float v = F_INF; unsigned int ix = 0;
    for (int t = lane; t < PS; t += 64) {
        float nv = pv[(size_t)row*PS + t];
        if (nv < v) { v = nv; ix = pi[(size_t)row*PS + t]; }
    }
    #pragma unroll
    for (int d = 1; d < 64; d <<= 1) {
        float ov = __shfl_xor(v, d);
        unsigned int oi = (unsigned int)__shfl_xor((int)ix, d);
        if (ov < v) { v = ov; ix = oi; }
    }
    const float4* q = reinterpret_cast<const float4*>(Q + (size_t)row * K) + lane*2;
    const float4* f = reinterpret_cast<const float4*>(F + (size_t)ix * K) + lane*2;
    float4 a0 = q[0], a1 = q[1], b0 = f[0], b1 = f[1];
    float s = 0.f, dx;
    dx = a0.x-b0.x; s += dx*dx;  dx = a0.y-b0.y; s += dx*dx;
    dx = a0.z-b0.z; s += dx*dx;  dx = a0.w-b0.w; s += dx*dx;
    dx = a1.x-b1.x; s += dx*dx;  dx = a1.y-b1.y; s += dx*dx;
    dx = a1.z-b1.z; s += dx*dx;  dx = a1.w-b1.w; s += dx*dx;
    #pragma unroll
    for (int d = 1; d < 64; d <<= 1) s += __shfl_xor(s, d);
    if (lane == 0) minD[row] = sqrtf(s);
}

// ---------------- K4: per-batch argmax patch (first-index tiebreak) ----------------
__global__ void k_argmax(const float* __restrict__ minD, unsigned int* __restrict__ sel) {
    __shared__ float sv[256];
    __shared__ int si[256];
    int b = blockIdx.x, tid = threadIdx.x;
    float bv = -F_INF; int bi = 0;
    for (int p = tid; p < 1024; p += 256) {
        float v = minD[b*1024 + p];
        if (v > bv) { bv = v; bi = p; }
    }
    sv[tid] = bv; si[tid] = bi;
    __syncthreads();
    for (int s = 128; s > 0; s >>= 1) {
        if (tid < s) {
            if (sv[tid+s] > sv[tid] || (sv[tid+s] == sv[tid] && si[tid+s] < si[tid])) {
                sv[tid] = sv[tid+s]; si[tid] = si[tid+s];
            }
        }
        __syncthreads();
    }
    if (tid == 0) sel[b] = (unsigned int)(b*1024 + si[0]);
}

// ---------------- K5-fast: distances from 8 selected rows to all F ----------------
__global__ void k_dist8(const float* __restrict__ Q, const float* __restrict__ F,
                        const unsigned int* __restrict__ sel, float* __restrict__ d2all) {
    __shared__ float qs[8][512];
    int tid = threadIdx.x;
    int lane = tid & 63, wave = tid >> 6;
    for (int i = tid; i < 8*512; i += 256) {
        int b = i >> 9;
        qs[b][i & 511] = Q[(size_t)sel[b] * K + (i & 511)];
    }
    __syncthreads();
    int base = blockIdx.x * 128 + wave * 32;
    for (int r = 0; r < 32; ++r) {
        int row = base + r;
        const float4* fp = reinterpret_cast<const float4*>(F + (size_t)row * K) + lane*2;
        float4 f0 = fp[0], f1 = fp[1];
        float fv[8] = {f0.x,f0.y,f0.z,f0.w,f1.x,f1.y,f1.z,f1.w};
        float accb[8];
        #pragma unroll
        for (int b = 0; b < 8; ++b) {
            float s = 0.f;
            #pragma unroll
            for (int e = 0; e < 8; ++e) {
                float d = fv[e] - qs[b][lane*8 + e];
                s += d * d;
            }
            accb[b] = s;
        }
        #pragma unroll
        for (int d = 1; d < 64; d <<= 1)
            #pragma unroll
            for (int b = 0; b < 8; ++b) accb[b] += __shfl_xor(accb[b], d);
        if (lane == 0) {
            #pragma unroll
            for (int b = 0; b < 8; ++b) d2all[b * N + row] = accb[b];
        }
    }
}

// ---------------- K6-fast: per-batch 9-smallest + score ----------------
__global__ void k_sel9(const float* __restrict__ d2all, float* __restrict__ out) {
    __shared__ float sv[256 * 10];
    int b = blockIdx.x, tid = threadIdx.x;
    float v[9];
    #pragma unroll
    for (int i = 0; i < 9; ++i) v[i] = F_INF;
    for (int i = tid; i < N; i += 256) {
        float x = d2all[b * N + i];
        #pragma unroll
        for (int s = 0; s < 9; ++s) {
            float lo = fminf(v[s], x), hi = fmaxf(v[s], x);
            v[s] = lo; x = hi;
        }
    }
    #pragma unroll
    for (int i = 0; i < 9; ++i) sv[tid*10 + i] = v[i];
    sv[tid*10 + 9] = F_INF;
    __syncthreads();
    for (int s = 128; s > 0; s >>= 1) {
        if (tid < s) {
            int ia = 1, ib = 1;
            float av = sv[tid*10], bv = sv[(tid+s)*10];
            float c[9];
            #pragma unroll
            for (int k = 0; k < 9; ++k) {
                bool ta = av <= bv;
                c[k] = ta ? av : bv;
                float na = sv[tid*10 + ia], nb = sv[(tid+s)*10 + ib];
                if (ta) { av = na; ++ia; } else { bv = nb; ++ib; }
            }
            #pragma unroll
            for (int k = 0; k < 9; ++k) sv[tid*10 + k] = c[k];
        }
        __syncthreads();
    }
    if (tid == 0) {
        float c[9];
        #pragma unroll
        for (int i = 0; i < 9; ++i) c[i] = sqrtf(fmaxf(sv[i], 0.f));
        float S = 0.f;
        #pragma unroll
        for (int i = 0; i < 9; ++i) S += expf(c[i] - c[8]);
        out[b] = c[0] * (1.f - 1.f / S);
    }
}

// ---------------- K5/K6-slow (fallback, R1-proven) ----------------
__global__ void k_top9(const float* __restrict__ Q, const float* __restrict__ F,
                       const unsigned int* __restrict__ sel, float* __restrict__ part9) {
    __shared__ float qs[512];
    __shared__ float dist[2048];
    __shared__ float rv[256];
    __shared__ int ri[256];
    int b = blockIdx.x >> 3, g = blockIdx.x & 7;
    int tid = threadIdx.x;
    unsigned int srow = sel[b];
    if (tid < 128)
        reinterpret_cast<float4*>(qs)[tid] =
            reinterpret_cast<const float4*>(Q + (size_t)srow * K)[tid];
    __syncthreads();
    #pragma unroll
    for (int e = 0; e < 8; ++e) {
        int fl = tid + 256*e;
        const float* fp = F + (size_t)(g*2048 + fl) * K;
        float s = 0.f;
        for (int k = 0; k < 512; k += 4) {
            float4 fv4 = *reinterpret_cast<const float4*>(fp + k);
            float d0 = qs[k]   - fv4.x;
            float d1 = qs[k+1] - fv4.y;
            float d2 = qs[k+2] - fv4.z;
            float d3 = qs[k+3] - fv4.w;
            s += d0*d0 + d1*d1 + d2*d2 + d3*d3;
        }
        dist[fl] = s;
    }
    __syncthreads();
    for (int it = 0; it < 9; ++it) {
        float lv = F_INF; int li = 0;
        #pragma unroll
        for (int e = 0; e < 8; ++e) {
            int idx = tid + 256*e;
            float v = dist[idx];
            if (v < lv) { lv = v; li = idx; }
        }
        rv[tid] = lv; ri[tid] = li;
        __syncthreads();
        for (int s = 128; s > 0; s >>= 1) {
            if (tid < s && rv[tid+s] < rv[tid]) { rv[tid] = rv[tid+s]; ri[tid] = ri[tid+s]; }
            __syncthreads();
        }
        if (tid == 0) {
            part9[(b*8+g)*9 + it] = rv[0];
            dist[ri[0]] = F_INF;
        }
        __syncthreads();
    }
}

__global__ void k_final(const float* __restrict__ part9, float* __restrict__ out) {
    int b = threadIdx.x;
    if (b >= 8) return;
    float arr[9];
    #pragma unroll
    for (int i = 0; i < 9; ++i) arr[i] = F_INF;
    for (int g = 0; g < 8; ++g)
        for (int i = 0; i < 9; ++i) {
            float v = part9[(b*8+g)*9 + i];
            #pragma unroll
            for (int s = 0; s < 9; ++s) {
                float lo = fminf(arr[s], v), hi = fmaxf(arr[s], v);
                arr[s] = lo; v = hi;
            }
        }
    float c[9];
    #pragma unroll
    for (int i = 0; i < 9; ++i) c[i] = sqrtf(fmaxf(arr[i], 0.f));
    float c8 = c[8], S = 0.f;
    #pragma unroll
    for (int i = 0; i < 9; ++i) S += expf(c[i] - c8);
    float w = 1.f - 1.f / S;
    out[b] = c[0] * w;
}

// ---------------- K7: combined (blur ∘ bilinear-resize) 256x32 matrix W ----------------
__global__ void k_wmat(float* __restrict__ W) {
    int idx = blockIdx.x * 256 + threadIdx.x;   // 8192
    int o = idx >> 5, j = idx & 31;
    float gsum = 0.f;
    #pragma unroll
    for (int u = 0; u < 33; ++u) { float d = (float)(u - 16); gsum += expf(-d*d * (1.f/32.f)); }
    float acc = 0.f;
    for (int u = 0; u < 33; ++u) {
        float d = (float)(u - 16);
        float gu = expf(-d*d * (1.f/32.f));
        int y = o + u - 16;
        y = y < 0 ? -y : (y > 255 ? 510 - y : y);   // reflect-101
        float xin = ((float)y + 0.5f) * 0.125f - 0.5f;
        float j0f = floorf(xin);
        int j0 = (int)j0f;
        float wfr = xin - j0f;
        float r;
        if (j0 < 0) r = (j == 0) ? 1.f : 0.f;
        else if (j0 >= 31) r = (j == 31) ? 1.f : 0.f;
        else r = (j == j0) ? (1.f - wfr) : ((j == j0 + 1) ? wfr : 0.f);
        acc += gu * r;
    }
    W[idx] = acc / gsum;
}

// ---------------- K8: mask = W * M32 * W^T per batch ----------------
__global__ void k_mask(const float* __restrict__ minD, const float* __restrict__ W,
                       float* __restrict__ outm) {
    __shared__ float Ms[1024];
    __shared__ float Ws[8192];
    __shared__ float Ts[8192];
    int b = blockIdx.x, tid = threadIdx.x;
    for (int i = tid; i < 1024; i += 256) Ms[i] = minD[b*1024 + i];
    for (int i = tid; i < 8192; i += 256) Ws[i] = W[i];
    __syncthreads();
    {
        int o = tid;
        float wrow[32];
        #pragma unroll
        for (int i = 0; i < 32; ++i) wrow[i] = Ws[o*32 + i];
        for (int j = 0; j < 32; ++j) {
            float s = 0.f;
            #pragma unroll
            for (int i = 0; i < 32; ++i) s += wrow[i] * Ms[i*32 + j];
            Ts[o*32 + j] = s;
        }
    }
    __syncthreads();
    {
        int p = tid;
        float wp[32];
        #pragma unroll
        for (int j = 0; j < 32; ++j) wp[j] = Ws[p*32 + j];
        float* dst = outm + (size_t)b * 65536;
        for (int o = 0; o < 256; ++o) {
            float s = 0.f;
            #pragma unroll
            for (int j = 0; j < 32; ++j) s += Ts[o*32 + j] * wp[j];
            dst[o*256 + p] = s;
        }
    }
}

extern "C" void kernel_launch(void* const* d_in, const int* in_sizes, int n_in,
                              void* d_out, int out_size, void* d_ws, size_t ws_size,
                              hipStream_t stream) {
    const float* Q = (const float*)d_in[0];          // [8192, 512]
    const float* F = (const float*)d_in[1];          // [16384, 512]
    float* out = (float*)d_out;                      // [8] score_out + [8*256*256] mask

    const size_t smallFloats = (size_t)8192*64*2 + 8192 + 8 + 576 + (size_t)8*N + 8192 + 16384 + 8192;
    const size_t REQ = smallFloats*4 + (size_t)M*K*2 + (size_t)N*K*2;
    const bool fast = ws_size >= REQ;

    float* ws = (float*)d_ws;
    float* pv = ws;                                    // stride 64 (fast) / 16 (slow)
    unsigned int* pi = (unsigned int*)(pv + 8192*64);
    float* minD = (float*)(pi + 8192*64);              // 8192
    unsigned int* sel = (unsigned int*)(minD + 8192);  // 8
    float* part9 = (float*)(sel + 8);                  // 576
    float* d2all = part9 + 576;                        // 8*16384 (fast only)
    float* qn = d2all + (size_t)8*N;                   // 8192
    float* fn = qn + 8192;                             // 16384
    float* W  = fn + 16384;                            // 8192
    unsigned short* Qb = (unsigned short*)(W + 8192);  // 8MB bf16 (fast only)
    unsigned short* Fb = Qb + (size_t)M*K;             // 16MB bf16 (fast only)

    k_wmat <<<dim3(32), 256, 0, stream>>>(W);
    if (fast) {
        k_prep <<<dim3((M + N) / 4), 256, 0, stream>>>(Q, F, Qb, Fb, qn, fn);
        k_mingemm9<<<dim3(RBLK * CBLK), 512, 0, stream>>>(Qb, Fb, qn, fn, pv, pi);
        k_refine<<<dim3(M / 4), 256, 0, stream>>>(Q, F, pv, pi, minD, 64);
        k_argmax<<<dim3(8), 256, 0, stream>>>(minD, sel);
        k_dist8<<<dim3(N / 128), 256, 0, stream>>>(Q, F, sel, d2all);
        k_sel9 <<<dim3(8), 256, 0, stream>>>(d2all, out);
    } else {
        k_norms<<<dim3((M + N) / 4), 256, 0, stream>>>(Q, F, qn, fn);
        k_mingemm_cast<<<dim3(M / BMs, NGROUPS_S), 256, 0, stream>>>(Q, F, qn, fn, pv, pi);
        k_refine<<<dim3(M / 4), 256, 0, stream>>>(Q, F, pv, pi, minD, 16);
        k_argmax<<<dim3(8), 256, 0, stream>>>(minD, sel);
        k_top9 <<<dim3(64), 256, 0, stream>>>(Q, F, sel, part9);
        k_final<<<dim3(1), 64, 0, stream>>>(part9, out);
    }
    k_mask <<<dim3(8), 256, 0, stream>>>(minD, W, out + 8);
}